// Round 1
// baseline (96.717 us; speedup 1.0000x reference)
//
#include <hip/hip_runtime.h>

#define BB 8
#define TT 2048
#define HH 256
#define LL 16

// wave-per-t: lane owns h-quad [4*lane, 4*lane+3]; 64 lanes cover H=256.
// Block = 256 threads = 4 waves = 4 consecutive t.
// bid & 7 -> b, so each batch (2 MB of logits) stays on one XCD's L2.
__global__ __launch_bounds__(256) void ffm_kernel(
    const float* __restrict__ logits,     // [B, T, H]
    const float* __restrict__ end_w,      // [H]
    const float* __restrict__ whole_w,    // [L, H]
    const float* __restrict__ relay_w,    // [H]
    const float* __restrict__ relay_b,    // [1]
    const float* __restrict__ length_bias,// [L]
    float* __restrict__ out)              // [B*T*L] then [B*T]
{
    const int tid  = threadIdx.x;
    const int lane = tid & 63;
    const int wv   = tid >> 6;
    const int bid  = blockIdx.x;
    const int b    = bid & 7;                 // XCD-aligned batch
    const int t    = ((bid >> 3) << 2) + wv;  // [0, T)

    const float4* lg4 = (const float4*)logits;   // [B*T, 64] float4 rows
    const int rowbase = (b * TT + t) * (HH / 4) + lane;

    const float4 cur = lg4[rowbase];

    // weights held in VGPRs for the whole kernel
    float4 ww[LL];
#pragma unroll
    for (int l = 0; l < LL; ++l)
        ww[l] = ((const float4*)whole_w)[l * (HH / 4) + lane];
    const float4 ew = ((const float4*)end_w)[lane];
    const float4 rw = ((const float4*)relay_w)[lane];

    float vals[18];

    // l = 0: max(cur, cur) = cur
    vals[0] = cur.x * ww[0].x + cur.y * ww[0].y + cur.z * ww[0].z + cur.w * ww[0].w;

#pragma unroll
    for (int l = 1; l < LL; ++l) {
        float4 row = make_float4(0.f, 0.f, 0.f, 0.f);
        if (t >= l) row = lg4[rowbase - l * (HH / 4)];   // left zero-pad: max with 0
        const float mx = fmaxf(cur.x, row.x);
        const float my = fmaxf(cur.y, row.y);
        const float mz = fmaxf(cur.z, row.z);
        const float mw = fmaxf(cur.w, row.w);
        vals[l] = mx * ww[l].x + my * ww[l].y + mz * ww[l].z + mw * ww[l].w;
    }

    // end score
    vals[16] = cur.x * ew.x + cur.y * ew.y + cur.z * ew.z + cur.w * ew.w;

    // relay: max(logits[t+L] or 0, logits[t])
    {
        float4 rr = make_float4(0.f, 0.f, 0.f, 0.f);
        if (t + LL < TT) rr = lg4[rowbase + LL * (HH / 4)];
        const float mx = fmaxf(cur.x, rr.x);
        const float my = fmaxf(cur.y, rr.y);
        const float mz = fmaxf(cur.z, rr.z);
        const float mw = fmaxf(cur.w, rr.w);
        vals[17] = mx * rw.x + my * rw.y + mz * rw.z + mw * rw.w;
    }

    // 64-lane butterfly reduction of all 18 partials
#pragma unroll
    for (int v = 0; v < 18; ++v) {
        float s = vals[v];
        s += __shfl_xor(s, 32);
        s += __shfl_xor(s, 16);
        s += __shfl_xor(s, 8);
        s += __shfl_xor(s, 4);
        s += __shfl_xor(s, 2);
        s += __shfl_xor(s, 1);
        vals[v] = s;
    }

    if (lane == 0) {
        const float ev = vals[16];
        float4* op = (float4*)(out + (size_t)(b * TT + t) * LL);
#pragma unroll
        for (int q = 0; q < 4; ++q) {
            float4 o;
            o.x = vals[q * 4 + 0] + ev + length_bias[q * 4 + 0];
            o.y = vals[q * 4 + 1] + ev + length_bias[q * 4 + 1];
            o.z = vals[q * 4 + 2] + ev + length_bias[q * 4 + 2];
            o.w = vals[q * 4 + 3] + ev + length_bias[q * 4 + 3];
            op[q] = o;
        }
        out[(size_t)BB * TT * LL + b * TT + t] = vals[17] + relay_b[0];
    }
}

extern "C" void kernel_launch(void* const* d_in, const int* in_sizes, int n_in,
                              void* d_out, int out_size, void* d_ws, size_t ws_size,
                              hipStream_t stream) {
    const float* logits  = (const float*)d_in[0];
    const float* end_w   = (const float*)d_in[1];
    const float* whole_w = (const float*)d_in[2];
    const float* relay_w = (const float*)d_in[3];
    const float* relay_b = (const float*)d_in[4];
    const float* lbias   = (const float*)d_in[5];
    float* out = (float*)d_out;

    dim3 grid(BB * TT / 4);   // 4096 blocks, 4 waves each, wave-per-t
    dim3 block(256);
    hipLaunchKernelGGL(ffm_kernel, grid, block, 0, stream,
                       logits, end_w, whole_w, relay_w, relay_b, lbias, out);
}

// Round 2
// 90.738 us; speedup vs baseline: 1.0659x; 1.0659x over previous
//
#include <hip/hip_runtime.h>

#define BB 8
#define TT 2048
#define HH 256
#define LL 16
#define SS 8                 // t's per wave (strip length)
#define NR (LL - 1 + SS)     // 23 rows resident: t-15 .. t+7

// Full-wave (64-lane) sum reduction on the VALU pipe via DPP.
// Result valid in lane 63 only. Zero DS-pipe instructions.
__device__ __forceinline__ float wave_sum_lane63(float v) {
    int x;
    x = __builtin_amdgcn_update_dpp(0, __float_as_int(v), 0x111, 0xf, 0xf, true); // row_shr:1
    v += __int_as_float(x);
    x = __builtin_amdgcn_update_dpp(0, __float_as_int(v), 0x112, 0xf, 0xf, true); // row_shr:2
    v += __int_as_float(x);
    x = __builtin_amdgcn_update_dpp(0, __float_as_int(v), 0x114, 0xf, 0xf, true); // row_shr:4
    v += __int_as_float(x);
    x = __builtin_amdgcn_update_dpp(0, __float_as_int(v), 0x118, 0xf, 0xf, true); // row_shr:8
    v += __int_as_float(x);
    // lane15=sum(row0), lane31=sum(row1), lane47=sum(row2), lane63=sum(row3)
    x = __builtin_amdgcn_update_dpp(0, __float_as_int(v), 0x142, 0xa, 0xf, true); // row_bcast:15, rows 1&3
    v += __int_as_float(x);
    // lane31=rows0+1, lane63=rows2+3
    x = __builtin_amdgcn_update_dpp(0, __float_as_int(v), 0x143, 0xc, 0xf, true); // row_bcast:31, rows 2&3
    v += __int_as_float(x);
    // lane63 = full 64-lane sum
    return v;
}

__device__ __forceinline__ float dotmax4(const float4 a, const float4 p, const float4 w) {
    return fmaxf(a.x, p.x) * w.x + fmaxf(a.y, p.y) * w.y +
           fmaxf(a.z, p.z) * w.z + fmaxf(a.w, p.w) * w.w;
}

// Wave-per-strip: each wave handles SS consecutive t for one b.
// Lane owns h-quad [4*lane .. 4*lane+3]; rows t-15..t+7 live in a VGPR ring,
// so each logits row is loaded from global exactly once (plus one relay row/t).
// Reduction is DPP (VALU pipe) — no LDS/DS traffic at all.
__global__ __launch_bounds__(256, 2) void ffm_kernel(
    const float* __restrict__ logits,      // [B, T, H]
    const float* __restrict__ end_w,       // [H]
    const float* __restrict__ whole_w,     // [L, H]
    const float* __restrict__ relay_w,     // [H]
    const float* __restrict__ relay_b,     // [1]
    const float* __restrict__ length_bias, // [L]
    float* __restrict__ out)               // [B*T*L] whole+end+bias, then [B*T] relay
{
    const int tid   = threadIdx.x;
    const int lane  = tid & 63;
    const int wv    = tid >> 6;
    const int bid   = blockIdx.x;
    const int b     = bid & 7;                          // XCD-aligned batch
    const int tbase = ((bid >> 3) * 4 + wv) * SS;       // strip start in [0, T)

    const float4* lg4 = (const float4*)logits;          // rows of 64 float4
    const long rowstr = HH / 4;                         // 64
    const long base   = (long)(b * TT) * rowstr + lane;

    const float4 z4 = make_float4(0.f, 0.f, 0.f, 0.f);

    // --- weights in VGPRs (amortized over SS t's) ---
    float4 ww[LL];
#pragma unroll
    for (int l = 0; l < LL; ++l)
        ww[l] = ((const float4*)whole_w)[l * rowstr + lane];
    const float4 ew = ((const float4*)end_w)[lane];
    const float4 rw = ((const float4*)relay_w)[lane];

    // epilogue constants (used by lane 63 only, loads are wave-uniform)
    float lb[LL];
#pragma unroll
    for (int q = 0; q < 4; ++q) {
        const float4 l4 = ((const float4*)length_bias)[q];
        lb[4 * q + 0] = l4.x; lb[4 * q + 1] = l4.y;
        lb[4 * q + 2] = l4.z; lb[4 * q + 3] = l4.w;
    }
    const float rb = relay_b[0];

    // --- load the row ring: rows tbase-15 .. tbase+7, each exactly once ---
    float4 rows[NR];
#pragma unroll
    for (int i = 0; i < NR; ++i) {
        const int r = tbase - (LL - 1) + i;             // wave-uniform
        rows[i] = (r >= 0) ? lg4[base + (long)r * rowstr] : z4;
    }

#pragma unroll
    for (int s = 0; s < SS; ++s) {
        const int t = tbase + s;
        const float4 cur = rows[LL - 1 + s];

        float vals[18];
#pragma unroll
        for (int l = 0; l < LL; ++l)
            vals[l] = dotmax4(cur, rows[LL - 1 + s - l], ww[l]);

        // end score: plain dot(cur, end_w)
        vals[16] = cur.x * ew.x + cur.y * ew.y + cur.z * ew.z + cur.w * ew.w;

        // relay: max(logits[t+16] or 0, cur) . relay_w
        float4 rr = z4;
        if (t + LL < TT) rr = lg4[base + (long)(t + LL) * rowstr];  // uniform guard
        vals[17] = dotmax4(cur, rr, rw);

        // 18 independent DPP reduction chains (VALU pipe, ILP across chains)
#pragma unroll
        for (int v = 0; v < 18; ++v)
            vals[v] = wave_sum_lane63(vals[v]);

        if (lane == 63) {
            const float ev = vals[16];
            float4* op = (float4*)(out + (size_t)(b * TT + t) * LL);
#pragma unroll
            for (int q = 0; q < 4; ++q) {
                float4 o;
                o.x = vals[4 * q + 0] + ev + lb[4 * q + 0];
                o.y = vals[4 * q + 1] + ev + lb[4 * q + 1];
                o.z = vals[4 * q + 2] + ev + lb[4 * q + 2];
                o.w = vals[4 * q + 3] + ev + lb[4 * q + 3];
                op[q] = o;
            }
            out[(size_t)BB * TT * LL + (size_t)(b * TT + t)] = vals[17] + rb;
        }
    }
}

extern "C" void kernel_launch(void* const* d_in, const int* in_sizes, int n_in,
                              void* d_out, int out_size, void* d_ws, size_t ws_size,
                              hipStream_t stream) {
    const float* logits  = (const float*)d_in[0];
    const float* end_w   = (const float*)d_in[1];
    const float* whole_w = (const float*)d_in[2];
    const float* relay_w = (const float*)d_in[3];
    const float* relay_b = (const float*)d_in[4];
    const float* lbias   = (const float*)d_in[5];
    float* out = (float*)d_out;

    // 2048 waves total (B*T/SS), 4 waves/block -> 512 blocks; all co-resident
    // at 2 waves/SIMD (launch_bounds 256,2).
    dim3 grid(BB * TT / (SS * 4));
    dim3 block(256);
    hipLaunchKernelGGL(ffm_kernel, grid, block, 0, stream,
                       logits, end_w, whole_w, relay_w, relay_b, lbias, out);
}

// Round 3
// 89.356 us; speedup vs baseline: 1.0824x; 1.0155x over previous
//
#include <hip/hip_runtime.h>

#define BB 8
#define TT 2048
#define HH 256
#define LL 16
#define SS 8                 // t's per wave (strip length)
#define NR (LL - 1 + SS)     // 23 rows resident: t-15 .. t+7

// Full-wave (64-lane) sum reduction on the VALU pipe via DPP; result in lane 63.
__device__ __forceinline__ float dpp_sum63(float v) {
    int x;
    x = __builtin_amdgcn_update_dpp(0, __float_as_int(v), 0x111, 0xf, 0xf, true); // row_shr:1
    v += __int_as_float(x);
    x = __builtin_amdgcn_update_dpp(0, __float_as_int(v), 0x112, 0xf, 0xf, true); // row_shr:2
    v += __int_as_float(x);
    x = __builtin_amdgcn_update_dpp(0, __float_as_int(v), 0x114, 0xf, 0xf, true); // row_shr:4
    v += __int_as_float(x);
    x = __builtin_amdgcn_update_dpp(0, __float_as_int(v), 0x118, 0xf, 0xf, true); // row_shr:8
    v += __int_as_float(x);
    x = __builtin_amdgcn_update_dpp(0, __float_as_int(v), 0x142, 0xa, 0xf, true); // row_bcast:15
    v += __int_as_float(x);
    x = __builtin_amdgcn_update_dpp(0, __float_as_int(v), 0x143, 0xc, 0xf, true); // row_bcast:31
    v += __int_as_float(x);
    return v;
}

__device__ __forceinline__ float dotmax4(const float4 a, const float4 p, const float4 w) {
    return fmaxf(a.x, p.x) * w.x + fmaxf(a.y, p.y) * w.y +
           fmaxf(a.z, p.z) * w.z + fmaxf(a.w, p.w) * w.w;
}

// Wave-per-strip, lane = h-quad, VGPR row ring (each logits row loaded once).
// Whole-score reduction = xor reduce-scatter: 4 select+shuffle halving steps put
// value v's group-partial on lanes with lane[3:0]==v, 2 xor-adds finish; every
// lane ends holding the full sum for l = lane & 15 -> coalesced 16-lane store.
__global__ __launch_bounds__(256, 2) void ffm_kernel(
    const float* __restrict__ logits,      // [B, T, H]
    const float* __restrict__ end_w,       // [H]
    const float* __restrict__ whole_w,     // [L, H]
    const float* __restrict__ relay_w,     // [H]
    const float* __restrict__ relay_b,     // [1]
    const float* __restrict__ length_bias, // [L]
    float* __restrict__ out)               // [B*T*L] then [B*T]
{
    const int tid   = threadIdx.x;
    const int lane  = tid & 63;
    const int wv    = tid >> 6;
    const int bid   = blockIdx.x;
    const int b     = bid & 7;                      // XCD-aligned batch
    const int tbase = ((bid >> 3) * 4 + wv) * SS;

    const float4* lg4 = (const float4*)logits;
    const long rowstr = HH / 4;                     // 64 float4 per row
    const long base   = (long)(b * TT) * rowstr + lane;
    const float4 z4 = make_float4(0.f, 0.f, 0.f, 0.f);

    float4 ww[LL];
#pragma unroll
    for (int l = 0; l < LL; ++l)
        ww[l] = ((const float4*)whole_w)[l * rowstr + lane];
    const float4 ew = ((const float4*)end_w)[lane];
    const float4 rw = ((const float4*)relay_w)[lane];
    const float lbv = length_bias[lane & 15];       // per-lane bias for epilogue
    const float rb  = relay_b[0];

    // row ring: tbase-15 .. tbase+7, each global row read exactly once
    float4 rows[NR];
#pragma unroll
    for (int i = 0; i < NR; ++i) {
        const int r = tbase - (LL - 1) + i;         // wave-uniform
        rows[i] = (r >= 0) ? lg4[base + (long)r * rowstr] : z4;
    }

#pragma unroll
    for (int s = 0; s < SS; ++s) {
        const int t = tbase + s;
        const float4 cur = rows[LL - 1 + s];

        float vals[LL];
#pragma unroll
        for (int l = 0; l < LL; ++l)
            vals[l] = dotmax4(cur, rows[LL - 1 + s - l], ww[l]);

        float ve = cur.x * ew.x + cur.y * ew.y + cur.z * ew.z + cur.w * ew.w;

        float4 rr = z4;
        if (t + LL < TT) rr = lg4[base + (long)(t + LL) * rowstr];  // uniform guard
        float vr = dotmax4(cur, rr, rw);

        // ---- xor reduce-scatter over the 16 whole values ----
        float a8[8];
#pragma unroll
        for (int k = 0; k < 8; ++k) {
            const float keep = (lane & 1) ? vals[2 * k + 1] : vals[2 * k];
            const float send = (lane & 1) ? vals[2 * k]     : vals[2 * k + 1];
            a8[k] = keep + __shfl_xor(send, 1);
        }
        float a4[4];
#pragma unroll
        for (int k = 0; k < 4; ++k) {
            const float keep = (lane & 2) ? a8[2 * k + 1] : a8[2 * k];
            const float send = (lane & 2) ? a8[2 * k]     : a8[2 * k + 1];
            a4[k] = keep + __shfl_xor(send, 2);
        }
        float a2[2];
#pragma unroll
        for (int k = 0; k < 2; ++k) {
            const float keep = (lane & 4) ? a4[2 * k + 1] : a4[2 * k];
            const float send = (lane & 4) ? a4[2 * k]     : a4[2 * k + 1];
            a2[k] = keep + __shfl_xor(send, 4);
        }
        float a1;
        {
            const float keep = (lane & 8) ? a2[1] : a2[0];
            const float send = (lane & 8) ? a2[0] : a2[1];
            a1 = keep + __shfl_xor(send, 8);
        }
        a1 += __shfl_xor(a1, 16);
        a1 += __shfl_xor(a1, 32);
        // a1 now holds the full 64-lane sum of whole[l = lane & 15] on every lane

        // end + relay on the VALU pipe (DPP), result in lane 63
        ve = dpp_sum63(ve);
        vr = dpp_sum63(vr);
        const float se = __int_as_float(
            __builtin_amdgcn_readlane(__float_as_int(ve), 63));  // uniform end score

        if (lane < 16)
            out[(size_t)(b * TT + t) * LL + lane] = a1 + se + lbv;
        if (lane == 63)
            out[(size_t)BB * TT * LL + (size_t)(b * TT + t)] = vr + rb;
    }
}

extern "C" void kernel_launch(void* const* d_in, const int* in_sizes, int n_in,
                              void* d_out, int out_size, void* d_ws, size_t ws_size,
                              hipStream_t stream) {
    const float* logits  = (const float*)d_in[0];
    const float* end_w   = (const float*)d_in[1];
    const float* whole_w = (const float*)d_in[2];
    const float* relay_w = (const float*)d_in[3];
    const float* relay_b = (const float*)d_in[4];
    const float* lbias   = (const float*)d_in[5];
    float* out = (float*)d_out;

    dim3 grid(BB * TT / (SS * 4));   // 512 blocks, 4 waves each, all co-resident
    dim3 block(256);
    hipLaunchKernelGGL(ffm_kernel, grid, block, 0, stream,
                       logits, end_w, whole_w, relay_w, relay_b, lbias, out);
}